// Round 11
// baseline (246.140 us; speedup 1.0000x reference)
//
#include <hip/hip_runtime.h>
#include <stdint.h>

// Problem: B=4096, S=256, F=64, K=16, L=256
//   logits[b,k,f] = sum_s x[b,s,f] * W[f,s,k]   (x NaN->0)
//   idx[b,f] = argmax_k logits[b,k,f]           (first max wins)
//   out[b,f,l] = snippet_list[f, idx[b,f], l]
constexpr int Bn = 4096, Sn = 256, Fn = 64, Kn = 16;

// W[f][s][k] -> Wl[s][kq][f][r]  (float4 view: Wl4[(s*4+kq)*64+f])
__global__ void transpose_w_kernel(const float* __restrict__ W, float* __restrict__ Wl) {
  int t = blockIdx.x * 256 + threadIdx.x;          // t = ((s*4+kq)*64+f)*4+r
  int r = t & 3, f = (t >> 2) & 63, kq = (t >> 8) & 3, s = t >> 10;
  Wl[t] = W[(f * Sn + s) * Kn + kq * 4 + r];
}

// GEMM+argmax, register-only W path (no LDS, no barriers in main loop).
// Grid 1024 x 256 threads (4 waves). All 4 waves of a block share batches
// b0 = blk*4 + {0..3}; wave w owns s-quarter [w*64, w*64+64). lane = f.
// Per round (1 s): 4 coalesced dwordx4 W loads (1 KB/wave, L2-resident
// transposed layout), 4 x dword loads (256 B/wave), 64 FMA.
// W double-buffered 1 round ahead; x double-buffered 2 rounds ahead.
// 16 waves/CU (4/SIMD). Live VGPR ~120 (acc 64 + wq 32 + x 12 + addr).
__global__ __launch_bounds__(256, 4) void gemm_argmax_kernel(
    const float* __restrict__ x, const float4* __restrict__ Wl4,
    int* __restrict__ idxg) {
  __shared__ float red[2][4][16][64];   // 32 KB, used only in epilogue

  const int tid = threadIdx.x;
  const int lane = tid & 63;            // f
  const int w = tid >> 6;               // s-quarter
  const int b0 = blockIdx.x * 4;
  const size_t xrow = (size_t)Sn * Fn;
  // x base for this wave's quarter: x[b0+j][w*64 + s][lane]
  const float* xp = x + (size_t)b0 * xrow + (size_t)(w * 64) * Fn + lane;
  // W base: Wl4[((w*64+s)*4+kq)*64 + lane] = wp[s*256 + kq*64]
  const float4* wp = Wl4 + (size_t)(w * 64) * 256 + lane;

  float acc[4][16];
#pragma unroll
  for (int j = 0; j < 4; ++j)
#pragma unroll
    for (int k = 0; k < 16; ++k) acc[j][k] = 0.f;

  float xA[4], xB[4];
  float4 wqA[4], wqB[4];

#define LOADW(s, wq)                                                  \
  {                                                                   \
    _Pragma("unroll") for (int kq = 0; kq < 4; ++kq)                  \
        wq[kq] = wp[(size_t)(s) * 256 + kq * 64];                     \
  }
#define LOADX(s, xb)                                                  \
  {                                                                   \
    _Pragma("unroll") for (int j = 0; j < 4; ++j)                     \
        xb[j] = xp[(size_t)j * xrow + (size_t)(s) * Fn];              \
  }
// one s-round: commit x (NaN->0), reissue x(s+2) into same buffer,
// issue W(s+1) into the other W buffer, then 64 FMAs from wq directly.
#define ROUND(s, xb, wq, wob)                                         \
  {                                                                   \
    float xv[4];                                                      \
    _Pragma("unroll") for (int j = 0; j < 4; ++j) {                   \
      float v = xb[j];                                                \
      xv[j] = (v == v) ? v : 0.f;                                     \
    }                                                                 \
    if ((s) + 2 < 64) LOADX((s) + 2, xb);                             \
    if ((s) + 1 < 64) LOADW((s) + 1, wob);                            \
    _Pragma("unroll") for (int j = 0; j < 4; ++j)                     \
        _Pragma("unroll") for (int kq = 0; kq < 4; ++kq) {            \
      acc[j][4 * kq + 0] = fmaf(xv[j], wq[kq].x, acc[j][4 * kq + 0]); \
      acc[j][4 * kq + 1] = fmaf(xv[j], wq[kq].y, acc[j][4 * kq + 1]); \
      acc[j][4 * kq + 2] = fmaf(xv[j], wq[kq].z, acc[j][4 * kq + 2]); \
      acc[j][4 * kq + 3] = fmaf(xv[j], wq[kq].w, acc[j][4 * kq + 3]); \
    }                                                                 \
  }

  // prologue: W(0), x(0), x(1) in flight
  LOADW(0, wqA);
  LOADX(0, xA);
  LOADX(1, xB);

  for (int s2 = 0; s2 < 64; s2 += 2) {
    ROUND(s2 + 0, xA, wqA, wqB);
    ROUND(s2 + 1, xB, wqB, wqA);
  }

  // two-round LDS tree reduce across the 4 s-quarter waves
  if (w >= 2) {
#pragma unroll
    for (int j = 0; j < 4; ++j)
#pragma unroll
      for (int k = 0; k < 16; ++k) red[w - 2][j][k][lane] = acc[j][k];
  }
  __syncthreads();
  if (w < 2) {
#pragma unroll
    for (int j = 0; j < 4; ++j)
#pragma unroll
      for (int k = 0; k < 16; ++k) acc[j][k] += red[w][j][k][lane];
  }
  if (w == 1) {
#pragma unroll
    for (int j = 0; j < 4; ++j)
#pragma unroll
      for (int k = 0; k < 16; ++k) red[1][j][k][lane] = acc[j][k];
  }
  __syncthreads();
  if (w == 0) {
#pragma unroll
    for (int j = 0; j < 4; ++j) {
#pragma unroll
      for (int k = 0; k < 16; ++k) acc[j][k] += red[1][j][k][lane];
      float bv = acc[j][0];
      int bk = 0;
#pragma unroll
      for (int k = 1; k < 16; ++k)
        if (acc[j][k] > bv) { bv = acc[j][k]; bk = k; }  // first max wins
      idxg[(b0 + j) * 64 + lane] = bk;
    }
  }
#undef LOADW
#undef LOADX
#undef ROUND
}

// Pure streaming gather: row r = b*64+f (262,144 rows of 1 KB).
__global__ __launch_bounds__(256) void gather_kernel(
    const int* __restrict__ idxg, const float4* __restrict__ snip4,
    float4* __restrict__ out4) {
  const int lane = threadIdx.x & 63;
  const int gw = (blockIdx.x * 256 + threadIdx.x) >> 6;
  const int r0 = gw * 16;
  int kk[16];
#pragma unroll
  for (int i = 0; i < 16; ++i) kk[i] = idxg[r0 + i];
#pragma unroll
  for (int i = 0; i < 16; ++i) {
    const int r = r0 + i;
    const int f = r & 63;
    out4[(size_t)r * 64 + lane] = snip4[(size_t)((f * Kn + kk[i]) * 64) + lane];
  }
}

// Fallback (ws too small): R5's verified fused kernel, direct W reads.
__global__ __launch_bounds__(256, 2) void fused_fallback(
    const float* __restrict__ x, const float* __restrict__ Wsrc,
    const float4* __restrict__ snip4, float4* __restrict__ out4) {
  __shared__ int idxs[8][64];
  const int tid = threadIdx.x;
  const int lane = tid & 63;
  const int w = tid >> 6;
  const int bbase = blockIdx.x * 8;
  const int b0 = bbase + w * 2;
  const size_t xrow = (size_t)Sn * Fn;

  float acc0[16], acc1[16];
#pragma unroll
  for (int k = 0; k < 16; ++k) { acc0[k] = 0.f; acc1[k] = 0.f; }
  const float* pc0 = x + (size_t)b0 * xrow + lane;
  const float* pc1 = pc0 + xrow;
  float xc0[8], xc1[8], xn0[8], xn1[8];
#pragma unroll
  for (int j = 0; j < 8; ++j) { xn0[j] = pc0[j * 64]; xn1[j] = pc1[j * 64]; }
  for (int c = 0; c < 32; ++c) {
#pragma unroll
    for (int j = 0; j < 8; ++j) {
      float v0 = xn0[j], v1 = xn1[j];
      xc0[j] = (v0 == v0) ? v0 : 0.f;
      xc1[j] = (v1 == v1) ? v1 : 0.f;
    }
    if (c < 31) {
      pc0 += 512; pc1 += 512;
#pragma unroll
      for (int j = 0; j < 8; ++j) { xn0[j] = pc0[j * 64]; xn1[j] = pc1[j * 64]; }
    }
#pragma unroll
    for (int s8 = 0; s8 < 8; ++s8) {
      const int s = c * 8 + s8;
      float wv[16];
      const float4* wq = reinterpret_cast<const float4*>(Wsrc) + ((size_t)(lane * Sn + s) << 2);
#pragma unroll
      for (int jj = 0; jj < 4; ++jj) {
        float4 q = wq[jj];
        wv[4 * jj + 0] = q.x; wv[4 * jj + 1] = q.y; wv[4 * jj + 2] = q.z; wv[4 * jj + 3] = q.w;
      }
#pragma unroll
      for (int k = 0; k < 16; ++k) {
        acc0[k] = fmaf(xc0[s8], wv[k], acc0[k]);
        acc1[k] = fmaf(xc1[s8], wv[k], acc1[k]);
      }
    }
  }
  {
    float bv0 = acc0[0], bv1 = acc1[0];
    int bk0 = 0, bk1 = 0;
#pragma unroll
    for (int k = 1; k < 16; ++k) {
      if (acc0[k] > bv0) { bv0 = acc0[k]; bk0 = k; }
      if (acc1[k] > bv1) { bv1 = acc1[k]; bk1 = k; }
    }
    idxs[w * 2 + 0][lane] = bk0;
    idxs[w * 2 + 1][lane] = bk1;
  }
  __syncthreads();
#pragma unroll 4
  for (int it = 0; it < 128; ++it) {
    int r = (it << 2) | w;
    int bi = r >> 6, f = r & 63;
    int kk = idxs[bi][f];
    float4 v = snip4[(size_t)((f * Kn + kk) << 6) + lane];
    out4[((size_t)(bbase + bi) * Fn + f) * 64 + lane] = v;
  }
}

extern "C" void kernel_launch(void* const* d_in, const int* in_sizes, int n_in,
                              void* d_out, int out_size, void* d_ws, size_t ws_size,
                              hipStream_t stream) {
  const float* x = (const float*)d_in[0];
  const float* W = (const float*)d_in[1];
  const float* snip = (const float*)d_in[2];
  float4* out4 = (float4*)d_out;
  const float4* snip4 = (const float4*)snip;

  const size_t wl_bytes = (size_t)Sn * Fn * Kn * sizeof(float);   // 1 MB
  const size_t idx_bytes = (size_t)Bn * Fn * sizeof(int);         // 1 MB
  if (ws_size >= wl_bytes + idx_bytes) {
    float* Wl = (float*)d_ws;
    int* idxg = (int*)((char*)d_ws + wl_bytes);
    transpose_w_kernel<<<(Sn * Fn * Kn) / 256, 256, 0, stream>>>(W, Wl);
    gemm_argmax_kernel<<<Bn / 4, 256, 0, stream>>>(x, (const float4*)Wl, idxg);
    gather_kernel<<<(Bn * Fn) / (4 * 16), 256, 0, stream>>>(idxg, snip4, out4);
  } else {
    fused_fallback<<<Bn / 8, 256, 0, stream>>>(x, W, snip4, out4);
  }
}

// Round 12
// 147.633 us; speedup vs baseline: 1.6672x; 1.6672x over previous
//
#include <hip/hip_runtime.h>
#include <stdint.h>

// Problem: B=4096, S=256, F=64, K=16, L=256
//   logits[b,k,f] = sum_s x[b,s,f] * W[f,s,k]   (x NaN->0)
//   idx[b,f] = argmax_k logits[b,k,f]           (first max wins)
//   out[b,f,l] = snippet_list[f, idx[b,f], l]
constexpr int Bn = 4096, Sn = 256, Fn = 64, Kn = 16;

// W[f][s][k] -> Wl[s][kq][f][r]  (float4 view: Wl4[(s*4+kq)*64+f])
__global__ void transpose_w_kernel(const float* __restrict__ W, float* __restrict__ Wl) {
  int t = blockIdx.x * 256 + threadIdx.x;          // t = ((s*4+kq)*64+f)*4+r
  int r = t & 3, f = (t >> 2) & 63, kq = (t >> 8) & 3, s = t >> 10;
  Wl[t] = W[(f * Sn + s) * Kn + kq * 4 + r];
}

// async global->LDS, 16B per lane; global src per-lane, LDS dest linear
__device__ __forceinline__ void gld_lds16(const float4* g, float4* l) {
  __builtin_amdgcn_global_load_lds(
      (const __attribute__((address_space(1))) uint32_t*)g,
      (__attribute__((address_space(3))) uint32_t*)l, 16, 0, 0);
}

// GEMM+argmax: bt=4, 2 s-halves, both operands via global_load_lds.
// Grid 256 x 512 threads (8 waves). wave w: wb=w&3 (batch quad),
// ws=w>>2 (s-half). Wave (wb,ws): batches blk*16+wb*4+{0..3},
// s in [ws*128, ws*128+128), 32 chunks of 4 s. lane = f.
// Per chunk/wave: stage W 4KB (4 gld_lds) + x 4KB (4 gld_lds), read back
// 16 ds_read_b128 (W) + 16 ds_read_b32 (x), 256 FMA. Double-buffered,
// one __syncthreads per chunk (its vmcnt0 drain completes the staging).
// LDS pipe/CU ~20us, x-HBM/CU ~42us (floor), FMA ~14us. VGPR ~100.
__global__ __launch_bounds__(512, 2) void gemm_argmax_kernel(
    const float* __restrict__ x, const float4* __restrict__ Wl4,
    int* __restrict__ idxg) {
  __shared__ float4 Wbuf[2][2][1024];    // [ws][p][s4*256+kq*64+f]   64 KB
  __shared__ float  xbuf[2][2][4][1024]; // [ws][p][wb][j*256+s4*64+f] 64 KB

  const int tid = threadIdx.x;
  const int lane = tid & 63;            // f
  const int w = tid >> 6;               // 0..7
  const int wb = w & 3;                 // batch quad
  const int ws = w >> 2;                // s-half
  const int b0 = blockIdx.x * 16 + wb * 4;
  const int lq = lane >> 4, lr = lane & 15;  // x-stage decomposition
  const int sbase = ws * 128;
  const float4* x4 = reinterpret_cast<const float4*>(x);

  float acc[4][16];
#pragma unroll
  for (int j = 0; j < 4; ++j)
#pragma unroll
    for (int k = 0; k < 16; ++k) acc[j][k] = 0.f;

// stage chunk c (4 s-rows) into parity p: W row (sbase+c*4+wb) = 4KB by
// this wave (4 x 1KB); x rows [c*4,c*4+4) of this wave's 4 batches
// (1KB per batch j: lane -> x[b0+j][s0+lq][lr*4..+4])
#define STAGE(c, p)                                                          \
  {                                                                          \
    const float4* _wsrc = Wl4 + (size_t)(sbase + (c) * 4 + wb) * 256 + lane; \
    float4* _wdst = &Wbuf[ws][p][wb * 256];                                  \
    _Pragma("unroll") for (int ii = 0; ii < 4; ++ii)                         \
        gld_lds16(_wsrc + ii * 64, _wdst + ii * 64);                         \
    float4* _xdst = reinterpret_cast<float4*>(&xbuf[ws][p][wb][0]);          \
    _Pragma("unroll") for (int j = 0; j < 4; ++j) {                          \
      const float4* _xsrc = x4 + (size_t)(b0 + j) * 4096 +                   \
                            (size_t)(sbase + (c) * 4 + lq) * 16 + lr;        \
      gld_lds16(_xsrc, _xdst + j * 64);                                      \
    }                                                                        \
  }

// compute chunk at parity p: 4 s-rows x 4 batches x 16 k
#define COMPUTE(p)                                                           \
  {                                                                          \
    _Pragma("unroll") for (int s4 = 0; s4 < 4; ++s4) {                       \
      float4 wq[4];                                                          \
      _Pragma("unroll") for (int kq = 0; kq < 4; ++kq)                       \
          wq[kq] = Wbuf[ws][p][s4 * 256 + kq * 64 + lane];                   \
      _Pragma("unroll") for (int j = 0; j < 4; ++j) {                        \
        float v = xbuf[ws][p][wb][j * 256 + s4 * 64 + lane];                 \
        float xv = (v == v) ? v : 0.f;                                       \
        _Pragma("unroll") for (int kq = 0; kq < 4; ++kq) {                   \
          acc[j][4 * kq + 0] = fmaf(xv, wq[kq].x, acc[j][4 * kq + 0]);       \
          acc[j][4 * kq + 1] = fmaf(xv, wq[kq].y, acc[j][4 * kq + 1]);       \
          acc[j][4 * kq + 2] = fmaf(xv, wq[kq].z, acc[j][4 * kq + 2]);       \
          acc[j][4 * kq + 3] = fmaf(xv, wq[kq].w, acc[j][4 * kq + 3]);       \
        }                                                                    \
      }                                                                      \
    }                                                                        \
  }

  STAGE(0, 0);
  __syncthreads();   // drain stage(0)

  for (int c = 0; c < 32; ++c) {
    const int p = c & 1;
    if (c + 1 < 32) STAGE(c + 1, p ^ 1);
    COMPUTE(p);
    __syncthreads(); // vmcnt0: stage(c+1) landed; all readers of p done
  }

  // cross-s-half reduce: reuse Wbuf (exactly 64 KB needed), then argmax
  float* red = reinterpret_cast<float*>(&Wbuf[0][0][0]);  // [(wb*4+j)*16+k][f]
  if (ws == 1) {
#pragma unroll
    for (int j = 0; j < 4; ++j)
#pragma unroll
      for (int k = 0; k < 16; ++k)
        red[((wb * 4 + j) * 16 + k) * 64 + lane] = acc[j][k];
  }
  __syncthreads();
  if (ws == 0) {
#pragma unroll
    for (int j = 0; j < 4; ++j) {
#pragma unroll
      for (int k = 0; k < 16; ++k)
        acc[j][k] += red[((wb * 4 + j) * 16 + k) * 64 + lane];
      float bv = acc[j][0];
      int bk = 0;
#pragma unroll
      for (int k = 1; k < 16; ++k)
        if (acc[j][k] > bv) { bv = acc[j][k]; bk = k; }  // first max wins
      idxg[(b0 + j) * 64 + lane] = bk;
    }
  }
#undef STAGE
#undef COMPUTE
}

// Pure streaming gather: row r = b*64+f (262,144 rows of 1 KB).
__global__ __launch_bounds__(256) void gather_kernel(
    const int* __restrict__ idxg, const float4* __restrict__ snip4,
    float4* __restrict__ out4) {
  const int lane = threadIdx.x & 63;
  const int gw = (blockIdx.x * 256 + threadIdx.x) >> 6;
  const int r0 = gw * 16;
  int kk[16];
#pragma unroll
  for (int i = 0; i < 16; ++i) kk[i] = idxg[r0 + i];
#pragma unroll
  for (int i = 0; i < 16; ++i) {
    const int r = r0 + i;
    const int f = r & 63;
    out4[(size_t)r * 64 + lane] = snip4[(size_t)((f * Kn + kk[i]) * 64) + lane];
  }
}

// Fallback (ws too small): R5's verified fused kernel, direct W reads.
__global__ __launch_bounds__(256, 2) void fused_fallback(
    const float* __restrict__ x, const float* __restrict__ Wsrc,
    const float4* __restrict__ snip4, float4* __restrict__ out4) {
  __shared__ int idxs[8][64];
  const int tid = threadIdx.x;
  const int lane = tid & 63;
  const int w = tid >> 6;
  const int bbase = blockIdx.x * 8;
  const int b0 = bbase + w * 2;
  const size_t xrow = (size_t)Sn * Fn;

  float acc0[16], acc1[16];
#pragma unroll
  for (int k = 0; k < 16; ++k) { acc0[k] = 0.f; acc1[k] = 0.f; }
  const float* pc0 = x + (size_t)b0 * xrow + lane;
  const float* pc1 = pc0 + xrow;
  float xc0[8], xc1[8], xn0[8], xn1[8];
#pragma unroll
  for (int j = 0; j < 8; ++j) { xn0[j] = pc0[j * 64]; xn1[j] = pc1[j * 64]; }
  for (int c = 0; c < 32; ++c) {
#pragma unroll
    for (int j = 0; j < 8; ++j) {
      float v0 = xn0[j], v1 = xn1[j];
      xc0[j] = (v0 == v0) ? v0 : 0.f;
      xc1[j] = (v1 == v1) ? v1 : 0.f;
    }
    if (c < 31) {
      pc0 += 512; pc1 += 512;
#pragma unroll
      for (int j = 0; j < 8; ++j) { xn0[j] = pc0[j * 64]; xn1[j] = pc1[j * 64]; }
    }
#pragma unroll
    for (int s8 = 0; s8 < 8; ++s8) {
      const int s = c * 8 + s8;
      float wv[16];
      const float4* wq = reinterpret_cast<const float4*>(Wsrc) + ((size_t)(lane * Sn + s) << 2);
#pragma unroll
      for (int jj = 0; jj < 4; ++jj) {
        float4 q = wq[jj];
        wv[4 * jj + 0] = q.x; wv[4 * jj + 1] = q.y; wv[4 * jj + 2] = q.z; wv[4 * jj + 3] = q.w;
      }
#pragma unroll
      for (int k = 0; k < 16; ++k) {
        acc0[k] = fmaf(xc0[s8], wv[k], acc0[k]);
        acc1[k] = fmaf(xc1[s8], wv[k], acc1[k]);
      }
    }
  }
  {
    float bv0 = acc0[0], bv1 = acc1[0];
    int bk0 = 0, bk1 = 0;
#pragma unroll
    for (int k = 1; k < 16; ++k) {
      if (acc0[k] > bv0) { bv0 = acc0[k]; bk0 = k; }
      if (acc1[k] > bv1) { bv1 = acc1[k]; bk1 = k; }
    }
    idxs[w * 2 + 0][lane] = bk0;
    idxs[w * 2 + 1][lane] = bk1;
  }
  __syncthreads();
#pragma unroll 4
  for (int it = 0; it < 128; ++it) {
    int r = (it << 2) | w;
    int bi = r >> 6, f = r & 63;
    int kk = idxs[bi][f];
    float4 v = snip4[(size_t)((f * Kn + kk) << 6) + lane];
    out4[((size_t)(bbase + bi) * Fn + f) * 64 + lane] = v;
  }
}

extern "C" void kernel_launch(void* const* d_in, const int* in_sizes, int n_in,
                              void* d_out, int out_size, void* d_ws, size_t ws_size,
                              hipStream_t stream) {
  const float* x = (const float*)d_in[0];
  const float* W = (const float*)d_in[1];
  const float* snip = (const float*)d_in[2];
  float4* out4 = (float4*)d_out;
  const float4* snip4 = (const float4*)snip;

  const size_t wl_bytes = (size_t)Sn * Fn * Kn * sizeof(float);   // 1 MB
  const size_t idx_bytes = (size_t)Bn * Fn * sizeof(int);         // 1 MB
  if (ws_size >= wl_bytes + idx_bytes) {
    float* Wl = (float*)d_ws;
    int* idxg = (int*)((char*)d_ws + wl_bytes);
    transpose_w_kernel<<<(Sn * Fn * Kn) / 256, 256, 0, stream>>>(W, Wl);
    gemm_argmax_kernel<<<Bn / 16, 512, 0, stream>>>(x, (const float4*)Wl, idxg);
    gather_kernel<<<(Bn * Fn) / (4 * 16), 256, 0, stream>>>(idxg, snip4, out4);
  } else {
    fused_fallback<<<Bn / 8, 256, 0, stream>>>(x, W, snip4, out4);
  }
}

// Round 13
// 133.901 us; speedup vs baseline: 1.8382x; 1.1026x over previous
//
#include <hip/hip_runtime.h>
#include <stdint.h>

// Problem: B=4096, S=256, F=64, K=16, L=256
//   logits[b,k,f] = sum_s x[b,s,f] * W[f,s,k]   (x NaN->0)
//   idx[b,f] = argmax_k logits[b,k,f]           (first max wins)
//   out[b,f,l] = snippet_list[f, idx[b,f], l]
constexpr int Bn = 4096, Sn = 256, Fn = 64, Kn = 16;

// W[f][s][k] -> Wl[s][kq][f][r]  (float4 view: Wl4[(s*4+kq)*64+f])
__global__ void transpose_w_kernel(const float* __restrict__ W, float* __restrict__ Wl) {
  int t = blockIdx.x * 256 + threadIdx.x;          // t = ((s*4+kq)*64+f)*4+r
  int r = t & 3, f = (t >> 2) & 63, kq = (t >> 8) & 3, s = t >> 10;
  Wl[t] = W[(f * Sn + s) * Kn + kq * 4 + r];
}

// async global->LDS, 16B per lane; LDS dest = wave-uniform base + lane*16
__device__ __forceinline__ void gld_lds16(const float4* g, float4* l) {
  __builtin_amdgcn_global_load_lds(
      (const __attribute__((address_space(1))) uint32_t*)g,
      (__attribute__((address_space(3))) uint32_t*)l, 16, 0, 0);
}

// FUSED gemm+argmax+gather (R8 main loop, proven ~115us, + R5 gather tail).
// Grid 512 x 256 threads (4 waves). Wave w owns batches b0=blk*8+w*2+{0,1}
// over FULL s (no cross-wave reduce). lane = f.
// W staged per 8-s chunk (32 KB) via global_load_lds, double-buffered
// (64 KB LDS -> 2 blocks/CU). x register-prefetched one chunk ahead.
// Epilogue: idx -> LDS, then each block gathers its own 512 output rows
// (1 KB each, coalesced float4) -- no separate gather kernel, no idx
// round-trip through global memory.
__global__ __launch_bounds__(256, 2) void fused_kernel(
    const float* __restrict__ x, const float4* __restrict__ Wl4,
    const float4* __restrict__ snip4, float4* __restrict__ out4) {
  __shared__ float4 Wbuf[2][2048];   // [parity][(s8*4+kq)*64 + f]  64 KB
  __shared__ int idxs[8][64];        // [b in block][f]              2 KB

  const int tid = threadIdx.x;
  const int lane = tid & 63;            // f
  const int w = tid >> 6;               // 0..3
  const int bbase = blockIdx.x * 8;
  const int b0 = bbase + w * 2;
  const size_t xrow = (size_t)Sn * Fn;
  const float* xb0 = x + (size_t)b0 * xrow + lane;

  float acc[2][16];
#pragma unroll
  for (int j = 0; j < 2; ++j)
#pragma unroll
    for (int k = 0; k < 16; ++k) acc[j][k] = 0.f;

  float xA[8][2], xB[8][2];

// stage W chunk c (8 s-rows = 2048 float4 = 32 KB) into Wbuf[p];
// wave w covers slices [w*8, w*8+8), 1024 B per gld_lds16
#define STAGEW(c, p)                                                         \
  {                                                                          \
    const float4* _src = Wl4 + (size_t)(c) * 2048 + (w * 8) * 64 + lane;     \
    float4* _dst = &Wbuf[p][(w * 8) * 64];                                   \
    _Pragma("unroll") for (int ii = 0; ii < 8; ++ii)                         \
        gld_lds16(_src + ii * 64, _dst + ii * 64);                           \
  }

// load x chunk c (8 s x 2 b, 256 B coalesced wave-loads) into reg buffer
#define LOADX(c, xn)                                                         \
  {                                                                          \
    _Pragma("unroll") for (int s8 = 0; s8 < 8; ++s8)                         \
        _Pragma("unroll") for (int j = 0; j < 2; ++j)                        \
            xn[s8][j] = xb0[(size_t)j * xrow + (size_t)((c) * 8 + s8) * Fn]; \
  }

// compute chunk from Wbuf[p] and reg buffer xn (NaN->0 applied at use)
#define COMPUTE(p, xn)                                                       \
  {                                                                          \
    _Pragma("unroll") for (int s8 = 0; s8 < 8; ++s8) {                       \
      float4 wq[4];                                                          \
      _Pragma("unroll") for (int kq = 0; kq < 4; ++kq)                       \
          wq[kq] = Wbuf[p][(s8 * 4 + kq) * 64 + lane];                       \
      float xv[2];                                                           \
      _Pragma("unroll") for (int j = 0; j < 2; ++j) {                        \
        float v = xn[s8][j];                                                 \
        xv[j] = (v == v) ? v : 0.f;                                          \
      }                                                                      \
      float wv[16];                                                          \
      _Pragma("unroll") for (int kq = 0; kq < 4; ++kq) {                     \
        wv[4 * kq + 0] = wq[kq].x; wv[4 * kq + 1] = wq[kq].y;                \
        wv[4 * kq + 2] = wq[kq].z; wv[4 * kq + 3] = wq[kq].w;                \
      }                                                                      \
      _Pragma("unroll") for (int j = 0; j < 2; ++j)                          \
          _Pragma("unroll") for (int k = 0; k < 16; ++k)                     \
              acc[j][k] = fmaf(xv[j], wv[k], acc[j][k]);                     \
    }                                                                        \
  }

  // prologue
  STAGEW(0, 0);
  LOADX(0, xA);
  __syncthreads();

  // 2-phase: stage next chunk before computing current; 1 barrier/chunk
  for (int cc = 0; cc < 32; cc += 2) {
    STAGEW(cc + 1, 1);
    LOADX(cc + 1, xB);
    COMPUTE(0, xA);
    __syncthreads();
    if (cc + 2 < 32) {
      STAGEW(cc + 2, 0);
      LOADX(cc + 2, xA);
    }
    COMPUTE(1, xB);
    __syncthreads();
  }

  // per-thread argmax (strict >, ascending k: first max wins) -> LDS
#pragma unroll
  for (int j = 0; j < 2; ++j) {
    float bv = acc[j][0];
    int bk = 0;
#pragma unroll
    for (int k = 1; k < 16; ++k)
      if (acc[j][k] > bv) { bv = acc[j][k]; bk = k; }
    idxs[w * 2 + j][lane] = bk;
  }
  __syncthreads();

  // fused gather: 8 b * 64 f = 512 rows of 1 KB; 4 consecutive rows per
  // round across the 4 waves -> 4 KB contiguous writes, fully coalesced.
  // snip (1 MB) is L2-resident; writes overlap other blocks' compute.
#pragma unroll 4
  for (int it = 0; it < 128; ++it) {
    int r = (it << 2) | w;
    int bi = r >> 6, f = r & 63;
    int kk = idxs[bi][f];
    float4 v = snip4[(size_t)((f * Kn + kk) << 6) + lane];
    out4[((size_t)(bbase + bi) * Fn + f) * 64 + lane] = v;
  }
#undef STAGEW
#undef LOADX
#undef COMPUTE
}

// Fallback (ws too small): R5's verified fused kernel, direct W reads.
__global__ __launch_bounds__(256, 2) void fused_fallback(
    const float* __restrict__ x, const float* __restrict__ Wsrc,
    const float4* __restrict__ snip4, float4* __restrict__ out4) {
  __shared__ int idxs[8][64];
  const int tid = threadIdx.x;
  const int lane = tid & 63;
  const int w = tid >> 6;
  const int bbase = blockIdx.x * 8;
  const int b0 = bbase + w * 2;
  const size_t xrow = (size_t)Sn * Fn;

  float acc0[16], acc1[16];
#pragma unroll
  for (int k = 0; k < 16; ++k) { acc0[k] = 0.f; acc1[k] = 0.f; }
  const float* pc0 = x + (size_t)b0 * xrow + lane;
  const float* pc1 = pc0 + xrow;
  float xc0[8], xc1[8], xn0[8], xn1[8];
#pragma unroll
  for (int j = 0; j < 8; ++j) { xn0[j] = pc0[j * 64]; xn1[j] = pc1[j * 64]; }
  for (int c = 0; c < 32; ++c) {
#pragma unroll
    for (int j = 0; j < 8; ++j) {
      float v0 = xn0[j], v1 = xn1[j];
      xc0[j] = (v0 == v0) ? v0 : 0.f;
      xc1[j] = (v1 == v1) ? v1 : 0.f;
    }
    if (c < 31) {
      pc0 += 512; pc1 += 512;
#pragma unroll
      for (int j = 0; j < 8; ++j) { xn0[j] = pc0[j * 64]; xn1[j] = pc1[j * 64]; }
    }
#pragma unroll
    for (int s8 = 0; s8 < 8; ++s8) {
      const int s = c * 8 + s8;
      float wv[16];
      const float4* wq = reinterpret_cast<const float4*>(Wsrc) + ((size_t)(lane * Sn + s) << 2);
#pragma unroll
      for (int jj = 0; jj < 4; ++jj) {
        float4 q = wq[jj];
        wv[4 * jj + 0] = q.x; wv[4 * jj + 1] = q.y; wv[4 * jj + 2] = q.z; wv[4 * jj + 3] = q.w;
      }
#pragma unroll
      for (int k = 0; k < 16; ++k) {
        acc0[k] = fmaf(xc0[s8], wv[k], acc0[k]);
        acc1[k] = fmaf(xc1[s8], wv[k], acc1[k]);
      }
    }
  }
  {
    float bv0 = acc0[0], bv1 = acc1[0];
    int bk0 = 0, bk1 = 0;
#pragma unroll
    for (int k = 1; k < 16; ++k) {
      if (acc0[k] > bv0) { bv0 = acc0[k]; bk0 = k; }
      if (acc1[k] > bv1) { bv1 = acc1[k]; bk1 = k; }
    }
    idxs[w * 2 + 0][lane] = bk0;
    idxs[w * 2 + 1][lane] = bk1;
  }
  __syncthreads();
#pragma unroll 4
  for (int it = 0; it < 128; ++it) {
    int r = (it << 2) | w;
    int bi = r >> 6, f = r & 63;
    int kk = idxs[bi][f];
    float4 v = snip4[(size_t)((f * Kn + kk) << 6) + lane];
    out4[((size_t)(bbase + bi) * Fn + f) * 64 + lane] = v;
  }
}

extern "C" void kernel_launch(void* const* d_in, const int* in_sizes, int n_in,
                              void* d_out, int out_size, void* d_ws, size_t ws_size,
                              hipStream_t stream) {
  const float* x = (const float*)d_in[0];
  const float* W = (const float*)d_in[1];
  const float* snip = (const float*)d_in[2];
  float4* out4 = (float4*)d_out;
  const float4* snip4 = (const float4*)snip;

  const size_t wl_bytes = (size_t)Sn * Fn * Kn * sizeof(float);   // 1 MB
  if (ws_size >= wl_bytes) {
    float* Wl = (float*)d_ws;
    transpose_w_kernel<<<(Sn * Fn * Kn) / 256, 256, 0, stream>>>(W, Wl);
    fused_kernel<<<Bn / 8, 256, 0, stream>>>(x, (const float4*)Wl, snip4, out4);
  } else {
    fused_fallback<<<Bn / 8, 256, 0, stream>>>(x, W, snip4, out4);
  }
}